// Round 10
// baseline (440.480 us; speedup 1.0000x reference)
//
#include <hip/hip_runtime.h>
#include <hip/hip_bf16.h>
#include <math.h>

#define B_ 4
#define S_ 2048
#define H_ 768
#define M_ (B_*S_)                 // 8192 rows
#define MN ((size_t)M_*(size_t)H_) // 6291456
#define HH (H_*H_)                 // 589824
#define SS ((size_t)S_*(size_t)S_)
#define SH ((size_t)S_*(size_t)H_)
#define NQKV 6912                  // 9 fused weight matrices
#define N3   2304                  // 3 fused weight matrices

typedef __bf16 bf16_t;
typedef __bf16 bf16x8 __attribute__((ext_vector_type(8)));
typedef __bf16 bf16x4 __attribute__((ext_vector_type(4)));
typedef float  f32x4  __attribute__((ext_vector_type(4)));
typedef unsigned short u16;
typedef u16 u16x4 __attribute__((ext_vector_type(4)));
typedef u16 u16x8 __attribute__((ext_vector_type(8)));

typedef __attribute__((address_space(3))) void       lds_void_t;
typedef __attribute__((address_space(1))) const void gvoid_t;

__device__ __forceinline__ float b2f(u16 u){ unsigned x = (unsigned)u << 16; float f; __builtin_memcpy(&f,&x,4); return f; }
__device__ __forceinline__ u16 f2b(float f){ bf16_t h = (bf16_t)f; u16 u; __builtin_memcpy(&u,&h,2); return u; }

template<bool MAXOP>
__device__ __forceinline__ float blockReduce(float v, float* s){
  #pragma unroll
  for (int o = 32; o; o >>= 1){
    float t = __shfl_xor(v, o);
    v = MAXOP ? fmaxf(v, t) : (v + t);
  }
  int lane = threadIdx.x & 63, w = threadIdx.x >> 6;
  if (lane == 0) s[w] = v;
  __syncthreads();
  float r = s[0];
  #pragma unroll
  for (int i = 1; i < 4; i++) r = MAXOP ? fmaxf(r, s[i]) : (r + s[i]);
  __syncthreads();
  return r;
}

__device__ __forceinline__ float waveMax(float v){
  #pragma unroll
  for (int o = 1; o < 64; o <<= 1) v = fmaxf(v, __shfl_xor(v, o));
  return v;
}
__device__ __forceinline__ float waveSum(float v){
  #pragma unroll
  for (int o = 1; o < 64; o <<= 1) v += __shfl_xor(v, o);
  return v;
}

// ---------------- weight conversion fp32 -> bf16; match (proto) plane scaled by 1/sqrt(d) ----------------
struct W18 { const float* p[18]; };

__global__ __launch_bounds__(256) void conv_weights(W18 w, bf16_t* __restrict__ out, float rs){
  int m = blockIdx.y;
  float sc = (m % 3 == 1) ? rs : 1.0f;
  int i = (blockIdx.x * 256 + threadIdx.x) * 4;   // grid.x*1024 == HH exactly
  f32x4 v = *(const f32x4*)(w.p[m] + i);
  bf16x4 o; o[0]=(bf16_t)(v[0]*sc); o[1]=(bf16_t)(v[1]*sc); o[2]=(bf16_t)(v[2]*sc); o[3]=(bf16_t)(v[3]*sc);
  *(bf16x4*)(out + (size_t)m * HH + i) = o;
}

// ---------------- LayerNorm (wave-per-row): fp32 in -> bf16 out ----------------
__global__ __launch_bounds__(256) void ln_kernel(const float* __restrict__ x,
                                                 const float* __restrict__ w,
                                                 const float* __restrict__ b,
                                                 bf16_t* __restrict__ outb){
  int wid = threadIdx.x >> 6, l = threadIdx.x & 63;
  int row = blockIdx.x * 4 + wid;
  size_t base = (size_t)row * H_ + l*12;
  float v[12];
  #pragma unroll
  for (int i = 0; i < 3; i++){
    f32x4 t = *(const f32x4*)(x + base + 4*i);
    #pragma unroll
    for (int j = 0; j < 4; j++) v[4*i+j] = t[j];
  }
  float s1 = 0.f, s2 = 0.f;
  #pragma unroll
  for (int j = 0; j < 12; j++){ s1 += v[j]; s2 += v[j]*v[j]; }
  s1 = waveSum(s1); s2 = waveSum(s2);
  float mu = s1 * (1.f/H_), var = s2 * (1.f/H_) - mu*mu;
  float rstd = rsqrtf(var + 1e-5f);
  #pragma unroll
  for (int i = 0; i < 3; i++){
    f32x4 wv = *(const f32x4*)(w + l*12 + 4*i);
    f32x4 bv = *(const f32x4*)(b + l*12 + 4*i);
    u16x4 u;
    #pragma unroll
    for (int j = 0; j < 4; j++) u[j] = f2b((v[4*i+j]-mu)*rstd*wv[j] + bv[j]);
    *(u16x4*)(outb + base + 4*i) = u;
  }
}

// ====================== 8-phase 256x256 BK=32 GEMM, 2 blocks/CU ======================
template<int MB, int NB>
__device__ __forceinline__ void quad(f32x4 (&acc)[8][4], bf16x8 (&aF)[8], bf16x8 (&bF)[4]){
  #pragma unroll
  for (int m = MB; m < MB+4; m++)
    #pragma unroll
    for (int n = NB; n < NB+2; n++)
      acc[m][n] = __builtin_amdgcn_mfma_f32_16x16x32_bf16(aF[m], bF[n], acc[m][n], 0,0,0);
}

// C = A * B^T, bf16 in/out. causal=1: triangle-compacted grid (36*B_ blocks).
// BK=32, 64 KiB LDS -> 2 blocks/CU; cross-block overlap hides barrier drains.
// Per K-tile (4 phases, 8 MFMA each):
//  ph0: read aF[0..3], bF[0,1]; stage Alow(t+1);  bar; lgkm0; Q(0,0); bar
//  ph1: read bF[2,3];           stage Ahigh(t+1); bar; lgkm0; Q(0,2); bar
//  ph2: read aF[4..7];          stage Blow(t+2);  bar; lgkm0; Q(4,0); bar
//  ph3:                         stage Bhigh(t+2); bar;        Q(4,2); vmcnt(2); bar
__global__ __launch_bounds__(512, 2) void gemm256ph(const bf16_t* __restrict__ A,
                                                    const bf16_t* __restrict__ Bm,
                                                    bf16_t* __restrict__ C,
                                                    int M, int N, int K,
                                                    long sA, long sB, long sC, int causal){
  extern __shared__ char smem[];   // A[2][16KB] | B[2][16KB] = 64 KiB
  char* Ab = smem;
  char* Bb = smem + 32768;

  int bx, by, z;
  if (causal){
    int id = blockIdx.x;           // grid = 36*B_ blocks, lower-triangle compaction
    z = id / 36; int t = id % 36;
    by = 0;
    while ((by+1)*(by+2)/2 <= t) by++;
    bx = t - by*(by+1)/2;
  } else {
    int gx = gridDim.x, gy = gridDim.y;
    int nwg = gx * gy;
    int id  = blockIdx.y * gx + blockIdx.x;
    int cpx = nwg >> 3;
    int nrb = cpx / gx;            // requires cpx % gx == 0
    int x = id & 7; int local = id >> 3;
    bx = local / nrb;
    by = x * nrb + (local % nrb);
    z = 0;
  }

  A  += (size_t)z * sA;
  Bm += (size_t)z * sB;
  C  += (size_t)z * sC;
  int row0 = by * 256, col0 = bx * 256;

  int tid = threadIdx.x, lane = tid & 63, wid = tid >> 6;
  int wm = wid >> 2, wn = wid & 3;        // 2x4 waves, 128x64 out each
  int lr = lane & 15, kg = lane >> 4;
  int NT = K >> 5;                         // BK = 32

  // stage one half-tile (128 rows x 32 bf16 = 8KB): 512 chunks, 1/thread.
  // slot sl in row rl holds global chunk sl^((rl>>1)&3) (involution; read matches).
  auto stA = [&](int buf, int h, int kt){
    int rl = tid >> 2, sl = tid & 3;
    const bf16_t* src = A + (size_t)(row0 + h*128 + rl)*K + kt*32 + (sl ^ ((rl>>1) & 3))*8;
    char* dst = Ab + buf*16384 + h*8192 + tid*16;
    __builtin_amdgcn_global_load_lds((gvoid_t*)src, (lds_void_t*)dst, 16, 0, 0);
  };
  auto stB = [&](int buf, int h, int kt){
    int rl = tid >> 2, sl = tid & 3;
    const bf16_t* src = Bm + (size_t)(col0 + h*128 + rl)*K + kt*32 + (sl ^ ((rl>>1) & 3))*8;
    char* dst = Bb + buf*16384 + h*8192 + tid*16;
    __builtin_amdgcn_global_load_lds((gvoid_t*)src, (lds_void_t*)dst, 16, 0, 0);
  };
  auto rd = [&](char* base, int buf, int r) -> bf16x8 {
    return *(const bf16x8*)(base + buf*16384 + r*64 + ((kg ^ ((r>>1) & 3))*16));
  };

  f32x4 acc[8][4] = {};
  bf16x8 aF[8], bF[4];

  // prologue: tile0 (A+B) + B(1); wait tile0, leave B(1)'s 2 loads in flight
  stA(0,0,0); stA(0,1,0); stB(0,0,0); stB(0,1,0);
  if (NT > 1){ stB(1,0,1); stB(1,1,1);
    asm volatile("s_waitcnt vmcnt(2)" ::: "memory");
  } else {
    asm volatile("s_waitcnt vmcnt(0)" ::: "memory");
  }
  __builtin_amdgcn_s_barrier();

  int buf = 0;
  for (int t = 0; t < NT; ++t){
    int nb = buf ^ 1;
    // ---- phase 0 ----
    #pragma unroll
    for (int m = 0; m < 4; m++) aF[m] = rd(Ab, buf, wm*128 + m*16 + lr);
    #pragma unroll
    for (int n = 0; n < 2; n++) bF[n] = rd(Bb, buf, wn*64 + n*16 + lr);
    if (t + 1 < NT) stA(nb, 0, t+1);
    __builtin_amdgcn_s_barrier();
    asm volatile("s_waitcnt lgkmcnt(0)" ::: "memory");
    __builtin_amdgcn_sched_barrier(0);
    __builtin_amdgcn_s_setprio(1);
    quad<0,0>(acc, aF, bF);
    __builtin_amdgcn_s_setprio(0);
    __builtin_amdgcn_s_barrier();
    // ---- phase 1 ----
    #pragma unroll
    for (int n = 2; n < 4; n++) bF[n] = rd(Bb, buf, wn*64 + n*16 + lr);
    if (t + 1 < NT) stA(nb, 1, t+1);
    __builtin_amdgcn_s_barrier();
    asm volatile("s_waitcnt lgkmcnt(0)" ::: "memory");
    __builtin_amdgcn_sched_barrier(0);
    __builtin_amdgcn_s_setprio(1);
    quad<0,2>(acc, aF, bF);
    __builtin_amdgcn_s_setprio(0);
    __builtin_amdgcn_s_barrier();
    // ---- phase 2 ----
    #pragma unroll
    for (int m = 4; m < 8; m++) aF[m] = rd(Ab, buf, wm*128 + m*16 + lr);
    if (t + 2 < NT) stB(buf, 0, t+2);
    __builtin_amdgcn_s_barrier();
    asm volatile("s_waitcnt lgkmcnt(0)" ::: "memory");
    __builtin_amdgcn_sched_barrier(0);
    __builtin_amdgcn_s_setprio(1);
    quad<4,0>(acc, aF, bF);
    __builtin_amdgcn_s_setprio(0);
    __builtin_amdgcn_s_barrier();
    // ---- phase 3 ----
    if (t + 2 < NT) stB(buf, 1, t+2);
    __builtin_amdgcn_s_barrier();
    __builtin_amdgcn_s_setprio(1);
    quad<4,2>(acc, aF, bF);
    __builtin_amdgcn_s_setprio(0);
    if (t + 2 < NT)      asm volatile("s_waitcnt vmcnt(2)" ::: "memory");
    else if (t + 1 < NT) asm volatile("s_waitcnt vmcnt(0)" ::: "memory");
    __builtin_amdgcn_s_barrier();
    buf = nb;
  }

  // epilogue: C/D layout col=lane&15, row=(lane>>4)*4+reg
  #pragma unroll
  for (int m = 0; m < 8; m++){
    int rb = row0 + wm*128 + m*16 + kg*4;
    #pragma unroll
    for (int n = 0; n < 4; n++){
      int cc = col0 + wn*64 + n*16 + lr;
      #pragma unroll
      for (int r = 0; r < 4; r++)
        C[(size_t)(rb + r)*N + cc] = (bf16_t)acc[m][n][r];
    }
  }
}

// ======================================================================
// 128x128 GEMM, ring-3 LDS, counted vmcnt (R6-proven). XOR swizzle
// (r>>1)&3. Column-major within XCD band. cmode: 0 none, 2 causal K-limit.
// ======================================================================
__global__ __launch_bounds__(256) void gemm_bt(const bf16_t* __restrict__ A,
                                               const bf16_t* __restrict__ Bm,
                                               bf16_t* __restrict__ C,
                                               int M, int N, int K,
                                               long sA, long sB, long sC, int cmode){
  __shared__ bf16_t As[3][128*32];
  __shared__ bf16_t Bs[3][128*32];

  int gx = gridDim.x, gy = gridDim.y;
  int nwg = gx * gy * gridDim.z;
  int id  = (blockIdx.z * gy + blockIdx.y) * gx + blockIdx.x;
  int cpx = nwg >> 3;
  int nrb = cpx / gx;
  int x   = id & 7;
  int local = id >> 3;
  int bx  = local / nrb;
  int frow = x * nrb + (local % nrb);
  int by  = frow % gy;
  int z   = frow / gy;

  A  += (size_t)z * sA;
  Bm += (size_t)z * sB;
  C  += (size_t)z * sC;

  int row0 = by * 128, col0 = bx * 128;

  int tid  = threadIdx.x;
  int lane = tid & 63;
  int wave = tid >> 6;
  int wm = wave >> 1, wn = wave & 1;
  int lr = lane & 15, kg = lane >> 4;

  f32x4 acc[4][4] = {};
  int NT = K >> 5;
  if (cmode == 2) { int lim = (row0 + 128) >> 5; NT = NT < lim ? NT : lim; }

  auto stage = [&](int buf, int kt){
    int kk = kt * 32;
    #pragma unroll
    for (int i = 0; i < 2; i++){
      int c  = tid + i*256;
      int r  = c >> 2;
      int scol = ((c & 3) ^ ((r >> 1) & 3)) * 8;
      __builtin_amdgcn_global_load_lds((gvoid_t*)(A  + (size_t)(row0 + r)*K + kk + scol),
                                       (lds_void_t*)(&As[buf][c*8]), 16, 0, 0);
      __builtin_amdgcn_global_load_lds((gvoid_t*)(Bm + (size_t)(col0 + r)*K + kk + scol),
                                       (lds_void_t*)(&Bs[buf][c*8]), 16, 0, 0);
    }
  };

  stage(0, 0);
  stage(1, 1);                                  // NT >= 2 for all our calls
  asm volatile("s_waitcnt vmcnt(4)" ::: "memory");
  __builtin_amdgcn_s_barrier();
  __builtin_amdgcn_sched_barrier(0);

  int b0 = 0, b1 = 1, b2 = 2;
  for (int kt = 0; kt < NT; ++kt){
    if (kt + 2 < NT) stage(b2, kt + 2);
    bf16x8 af[4], bfr[4];
    #pragma unroll
    for (int m = 0; m < 4; m++){
      int r = wm*64 + m*16 + lr;
      af[m] = *reinterpret_cast<const bf16x8*>(&As[b0][r*32 + ((kg ^ ((r >> 1) & 3)) * 8)]);
    }
    #pragma unroll
    for (int n = 0; n < 4; n++){
      int r = wn*64 + n*16 + lr;
      bfr[n] = *reinterpret_cast<const bf16x8*>(&Bs[b0][r*32 + ((kg ^ ((r >> 1) & 3)) * 8)]);
    }
    #pragma unroll
    for (int m = 0; m < 4; m++)
      #pragma unroll
      for (int n = 0; n < 4; n++)
        acc[m][n] = __builtin_amdgcn_mfma_f32_16x16x32_bf16(af[m], bfr[n], acc[m][n], 0, 0, 0);
    if (kt + 1 < NT){
      if (kt + 2 < NT) asm volatile("s_waitcnt vmcnt(4)" ::: "memory");
      else             asm volatile("s_waitcnt vmcnt(0)" ::: "memory");
      __builtin_amdgcn_s_barrier();
      __builtin_amdgcn_sched_barrier(0);
    }
    int tmp = b0; b0 = b1; b1 = b2; b2 = tmp;
  }

  #pragma unroll
  for (int m = 0; m < 4; m++){
    int rb = row0 + wm*64 + m*16 + kg*4;
    #pragma unroll
    for (int n = 0; n < 4; n++){
      int cc = col0 + wn*64 + n*16 + lr;
      #pragma unroll
      for (int r = 0; r < 4; r++)
        C[(size_t)(rb + r)*N + cc] = (bf16_t)acc[m][n][r];
    }
  }
}

// ---------------- merged QKV gate: wave-per-row, 3 sections ----------------
__global__ __launch_bounds__(256) void gate_qkv(const bf16_t* __restrict__ inp,
                                                const bf16_t* __restrict__ c3,
                                                const float* __restrict__ b_q,
                                                const float* __restrict__ b_k,
                                                const float* __restrict__ b_v,
                                                const float* __restrict__ cosT,
                                                const float* __restrict__ sinT,
                                                bf16_t* __restrict__ q_o,
                                                bf16_t* __restrict__ k_o,
                                                bf16_t* __restrict__ v_o,
                                                float rs){
  int wid = threadIdx.x >> 6, l = threadIdx.x & 63;
  int row = blockIdx.x * 4 + wid;
  size_t bi = (size_t)row * H_ + l*12;
  size_t brow = (size_t)row * NQKV + l*12;

  float iv[12];
  #pragma unroll
  for (int i = 0; i < 3; i++){
    u16x4 a = *(const u16x4*)(inp + bi + 4*i);
    #pragma unroll
    for (int j = 0; j < 4; j++) iv[4*i+j] = b2f(a[j]);
  }
  int s = row & (S_ - 1);
  f32x4 cw[3], sw[3];
  #pragma unroll
  for (int i = 0; i < 3; i++){
    cw[i] = *(const f32x4*)(cosT + (size_t)s*H_ + l*12 + 4*i);
    sw[i] = *(const f32x4*)(sinT + (size_t)s*H_ + l*12 + 4*i);
  }

  const float* biasp[3] = {b_q, b_k, b_v};
  bf16_t* outp[3] = {q_o, k_o, v_o};

  #pragma unroll
  for (int sec = 0; sec < 3; sec++){
    size_t bc = brow + (size_t)sec * 2304;
    float cv[12], mv[12], gv[12];
    float gmax = 0.f;
    #pragma unroll
    for (int i = 0; i < 3; i++){
      u16x4 b = *(const u16x4*)(c3 + bc + 4*i);
      u16x4 c = *(const u16x4*)(c3 + bc + 768 + 4*i);
      u16x4 d = *(const u16x4*)(c3 + bc + 1536 + 4*i);
      f32x4 bv = *(const f32x4*)(biasp[sec] + l*12 + 4*i);
      #pragma unroll
      for (int j = 0; j < 4; j++){
        cv[4*i+j] = b2f(b[j]) + bv[j];
        mv[4*i+j] = b2f(c[j]);
        gv[4*i+j] = b2f(d[j]);
        gmax = fmaxf(gmax, fabsf(gv[4*i+j]));
      }
    }
    gmax = waveMax(gmax);
    float rg = 1.f / (gmax + 1e-9f);
    float rt[12], rmax = 0.f;
    #pragma unroll
    for (int j = 0; j < 12; j++){
      rt[j] = mv[j] - fmaxf(gv[j]*rg, 0.f);
      rmax  = fmaxf(rmax, fabsf(rt[j]));
    }
    rmax = waveMax(rmax);
    float rr = 1.f / (rmax + 1e-9f);
    float oscale = (sec == 0) ? rs : 1.0f;
    float val[12];
    #pragma unroll
    for (int j = 0; j < 12; j++) val[j] = (iv[j] + cv[j]) * fmaxf(rt[j]*rr, 0.f) * oscale;

    if (sec < 2){
      #pragma unroll
      for (int i = 0; i < 3; i++){
        u16x4 u;
        #pragma unroll
        for (int j = 0; j < 4; j++){
          int q = 4*i + j;
          float partner = __shfl_xor(val[q], 32);
          if (l < 32) partner = -partner;
          u[j] = f2b(val[q]*cw[i][j] + partner*sw[i][j]);
        }
        *(u16x4*)(outp[sec] + bi + 4*i) = u;
      }
    } else {
      #pragma unroll
      for (int i = 0; i < 3; i++){
        u16x4 u;
        #pragma unroll
        for (int j = 0; j < 4; j++) u[j] = f2b(val[4*i+j]);
        *(u16x4*)(outp[sec] + bi + 4*i) = u;
      }
    }
  }
}

// ---------------- gate branch: wave-per-row ----------------
// mode 2: +resid -> outf ; 3: relu -> outb ; 4: +resid -> outf AND LN -> outb
__global__ __launch_bounds__(256) void gate_kernel(const bf16_t* __restrict__ inp,
                                                   const bf16_t* __restrict__ c3,
                                                   long ldc, int colbase,
                                                   const float* __restrict__ bias,
                                                   const float* __restrict__ resid,
                                                   const float* __restrict__ lnw,
                                                   const float* __restrict__ lnb,
                                                   float* __restrict__ outf,
                                                   bf16_t* __restrict__ outb,
                                                   int mode){
  int wid = threadIdx.x >> 6, l = threadIdx.x & 63;
  int row = blockIdx.x * 4 + wid;
  size_t bi = (size_t)row * H_ + l*12;
  size_t bc = (size_t)row * ldc + colbase + l*12;

  float iv[12], cv[12], mv[12], gv[12];
  float gmax = 0.f;
  #pragma unroll
  for (int i = 0; i < 3; i++){
    u16x4 a = *(const u16x4*)(inp + bi + 4*i);
    u16x4 b = *(const u16x4*)(c3 + bc + 4*i);
    u16x4 c = *(const u16x4*)(c3 + bc + 768 + 4*i);
    u16x4 d = *(const u16x4*)(c3 + bc + 1536 + 4*i);
    f32x4 bv = *(const f32x4*)(bias + l*12 + 4*i);
    #pragma unroll
    for (int j = 0; j < 4; j++){
      iv[4*i+j] = b2f(a[j]); cv[4*i+j] = b2f(b[j]) + bv[j];
      mv[4*i+j] = b2f(c[j]); gv[4*i+j] = b2f(d[j]);
      gmax = fmaxf(gmax, fabsf(gv[4*i+j]));
    }
  }
  gmax = waveMax(gmax);
  float rg = 1.f / (gmax + 1e-9f);

  float rt[12], rmax = 0.f;
  #pragma unroll
  for (int j = 0; j < 12; j++){
    rt[j] = mv[j] - fmaxf(gv[j]*rg, 0.f);
    rmax  = fmaxf(rmax, fabsf(rt[j]));
  }
  rmax = waveMax(rmax);
  float rr = 1.f / (rmax + 1e-9f);

  float val[12];
  #pragma unroll
  for (int j = 0; j < 12; j++) val[j] = (iv[j] + cv[j]) * fmaxf(rt[j]*rr, 0.f);

  if (mode == 3){
    #pragma unroll
    for (int i = 0; i < 3; i++){
      u16x4 u;
      #pragma unroll
      for (int j = 0; j < 4; j++) u[j] = f2b(fmaxf(val[4*i+j], 0.f));
      *(u16x4*)(outb + bi + 4*i) = u;
    }
  } else if (mode == 2){
    #pragma unroll
    for (int i = 0; i < 3; i++){
      f32x4 rv = *(const f32x4*)(resid + bi + 4*i);
      f32x4 ov;
      #pragma unroll
      for (int j = 0; j < 4; j++) ov[j] = val[4*i+j] + rv[j];
      *(f32x4*)(outf + bi + 4*i) = ov;
    }
  } else { // mode 4
    float xv[12];
    #pragma unroll
    for (int i = 0; i < 3; i++){
      f32x4 rv = *(const f32x4*)(resid + bi + 4*i);
      f32x4 ov;
      #pragma unroll
      for (int j = 0; j < 4; j++){ xv[4*i+j] = val[4*i+j] + rv[j]; ov[j] = xv[4*i+j]; }
      *(f32x4*)(outf + bi + 4*i) = ov;
    }
    float s1 = 0.f, s2 = 0.f;
    #pragma unroll
    for (int j = 0; j < 12; j++){ s1 += xv[j]; s2 += xv[j]*xv[j]; }
    s1 = waveSum(s1); s2 = waveSum(s2);
    float mu = s1 * (1.f/H_), var = s2 * (1.f/H_) - mu*mu;
    float rstd = rsqrtf(var + 1e-5f);
    #pragma unroll
    for (int i = 0; i < 3; i++){
      f32x4 wv = *(const f32x4*)(lnw + l*12 + 4*i);
      f32x4 bv = *(const f32x4*)(lnb + l*12 + 4*i);
      u16x4 u;
      #pragma unroll
      for (int j = 0; j < 4; j++) u[j] = f2b((xv[4*i+j]-mu)*rstd*wv[j] + bv[j]);
      *(u16x4*)(outb + bi + 4*i) = u;
    }
  }
}

// ---------------- single-pass causal softmax: 8 cols/thread in registers ----------------
__global__ __launch_bounds__(256) void softmax_causal(const bf16_t* __restrict__ sc,
                                                      bf16_t* __restrict__ P){
  __shared__ float red[4];
  int r = blockIdx.x, b = blockIdx.y, t = threadIdx.x;
  const bf16_t* srow = sc + (size_t)b*SS + (size_t)r * S_;
  bf16_t* prow = P + (size_t)b*SS + (size_t)r * S_;
  int n = r + 1;
  int fill = ((r >> 7) + 1) << 7;          // PV reads k < row0+128; zero up to there
  int c0 = t * 8;

  float v[8];
  float m = -1e30f;
  if (c0 < n){
    u16x8 u = *(const u16x8*)(srow + c0);
    #pragma unroll
    for (int j = 0; j < 8; j++){
      v[j] = (c0 + j < n) ? b2f(u[j]) : -1e30f;
      m = fmaxf(m, v[j]);
    }
  } else {
    #pragma unroll
    for (int j = 0; j < 8; j++) v[j] = -1e30f;
  }
  m = blockReduce<true>(m, red);
  float sum = 0.f;
  #pragma unroll
  for (int j = 0; j < 8; j++){
    v[j] = (v[j] > -1e29f) ? __expf(v[j] - m) : 0.f;
    sum += v[j];
  }
  sum = blockReduce<false>(sum, red);
  float inv = 1.f / sum;
  if (c0 < fill){
    u16x8 u;
    #pragma unroll
    for (int j = 0; j < 8; j++) u[j] = f2b(v[j] * inv);
    *(u16x8*)(prow + c0) = u;
  }
}

// ---------------- 32x32 tiled transpose [B,S,H] -> [B,H,S] ----------------
__global__ __launch_bounds__(256) void transpose_bf(const bf16_t* __restrict__ in,
                                                    bf16_t* __restrict__ out){
  __shared__ bf16_t tile[32][33];
  int bz = blockIdx.z;
  const bf16_t* I = in  + (size_t)bz * SH;
  bf16_t*       O = out + (size_t)bz * SH;
  int s0 = blockIdx.x*32, h0 = blockIdx.y*32;
  int tx = threadIdx.x, ty = threadIdx.y;
  #pragma unroll
  for (int k = 0; k < 4; k++)
    tile[ty + 8*k][tx] = I[(size_t)(s0 + ty + 8*k)*H_ + h0 + tx];
  __syncthreads();
  #pragma unroll
  for (int k = 0; k < 4; k++)
    O[(size_t)(h0 + ty + 8*k)*S_ + s0 + tx] = tile[tx][ty + 8*k];
}

// ---------------- launch ----------------
extern "C" void kernel_launch(void* const* d_in, const int* in_sizes, int n_in,
                              void* d_out, int out_size, void* d_ws, size_t ws_size,
                              hipStream_t stream){
  const float* x    = (const float*)d_in[0];
  const float* cosT = (const float*)d_in[1];
  const float* sinT = (const float*)d_in[2];
  const float* ln1w = (const float*)d_in[3];
  const float* ln1b = (const float*)d_in[4];
  const float* ln2w = (const float*)d_in[5];
  const float* ln2b = (const float*)d_in[6];

  W18 wp; const float* bias[6];
  for (int i = 0; i < 6; i++){
    const float* proto = (const float*)d_in[7 + 4*i + 0];
    const float* gatep = (const float*)d_in[7 + 4*i + 1];
    const float* muw   = (const float*)d_in[7 + 4*i + 2];
    bias[i]            = (const float*)d_in[7 + 4*i + 3];
    wp.p[i*3 + 0] = muw;    // comp
    wp.p[i*3 + 1] = proto;  // match (scaled by rs at conversion)
    wp.p[i*3 + 2] = gatep;  // gate
  }

  hipFuncSetAttribute((const void*)gemm256ph, hipFuncAttributeMaxDynamicSharedMemorySize, 65536);

  char* w = (char*)d_ws;
  auto alloc = [&](size_t bytes){ void* r = (void*)w; w += (bytes + 255) & ~(size_t)255; return r; };
  bf16_t* w_bf   = (bf16_t*)alloc((size_t)18 * HH * 2);      // [13824, 768]
  bf16_t* a_bf   = (bf16_t*)alloc(MN * 2);
  bf16_t* h_bf   = (bf16_t*)alloc(MN * 2);
  bf16_t* c3b    = (bf16_t*)alloc((size_t)M_ * NQKV * 2);    // logits; overlays scores+P
  bf16_t* q_bf   = (bf16_t*)alloc(MN * 2);
  bf16_t* k_bf   = (bf16_t*)alloc(MN * 2);
  bf16_t* v_bf   = (bf16_t*)alloc(MN * 2);
  bf16_t* vt     = (bf16_t*)alloc(MN * 2);
  bf16_t* attn_b = (bf16_t*)alloc(MN * 2);
  float*  x1     = (float*) alloc(MN * 4);
  (void)ws_size;
  bf16_t* sc_bf = c3b;
  bf16_t* p_bf  = c3b + B_ * SS;

  const float rs = 1.0f / sqrtf((float)H_);

  conv_weights<<<dim3(HH/1024, 18), 256, 0, stream>>>(wp, w_bf, rs);
  ln_kernel<<<M_/4, 256, 0, stream>>>(x, ln1w, ln1b, a_bf);

  // QKV fused SPL: c3b[M, 6912]  — 8-phase 256^2 BK=32 kernel
  gemm256ph<<<dim3(NQKV/256, M_/256, 1), 512, 65536, stream>>>(
      a_bf, w_bf, c3b, M_, NQKV, H_, 0, 0, 0, 0);
  gate_qkv<<<M_/4, 256, 0, stream>>>(a_bf, c3b, bias[0], bias[1], bias[2],
                                     cosT, sinT, q_bf, k_bf, v_bf, rs);

  transpose_bf<<<dim3(S_/32, H_/32, B_), dim3(32, 8), 0, stream>>>(v_bf, vt);

  // QK^T (scale folded into q) — 8-phase, triangle-compacted grid
  gemm256ph<<<dim3(36*B_, 1, 1), 512, 65536, stream>>>(
      q_bf, k_bf, sc_bf, S_, S_, H_, (long)SH, (long)SH, (long)SS, 1);

  softmax_causal<<<dim3(S_, B_), 256, 0, stream>>>(sc_bf, p_bf);

  // PV (K limited causally) — ring-3 128^2
  gemm_bt<<<dim3(H_/128, S_/128, B_), 256, 0, stream>>>(
      p_bf, vt, attn_b, S_, H_, S_, (long)SS, (long)SH, (long)SH, 2);

  // o-SPL + gate(+residual x) + fused LN2 -> x1 and a_bf
  gemm_bt<<<dim3(N3/128, M_/128, 1), 256, 0, stream>>>(
      attn_b, w_bf + (size_t)9*HH, c3b, M_, N3, H_, 0, 0, 0, 0);
  gate_kernel<<<M_/4, 256, 0, stream>>>(attn_b, c3b, N3, 0, bias[3], x, ln2w, ln2b, x1, a_bf, 4);

  // f1-SPL + gate + relu -> h_bf
  gemm_bt<<<dim3(N3/128, M_/128, 1), 256, 0, stream>>>(
      a_bf, w_bf + (size_t)12*HH, c3b, M_, N3, H_, 0, 0, 0, 0);
  gate_kernel<<<M_/4, 256, 0, stream>>>(a_bf, c3b, N3, 0, bias[4], nullptr, nullptr, nullptr, nullptr, h_bf, 3);

  // f2-SPL + gate(+residual x1) -> d_out
  gemm_bt<<<dim3(N3/128, M_/128, 1), 256, 0, stream>>>(
      h_bf, w_bf + (size_t)15*HH, c3b, M_, N3, H_, 0, 0, 0, 0);
  gate_kernel<<<M_/4, 256, 0, stream>>>(h_bf, c3b, N3, 0, bias[5], x1, nullptr, nullptr, (float*)d_out, nullptr, 2);
}

// Round 11
// 438.081 us; speedup vs baseline: 1.0055x; 1.0055x over previous
//
#include <hip/hip_runtime.h>
#include <hip/hip_bf16.h>
#include <math.h>

#define B_ 4
#define S_ 2048
#define H_ 768
#define M_ (B_*S_)                 // 8192 rows
#define MN ((size_t)M_*(size_t)H_) // 6291456
#define HH (H_*H_)                 // 589824
#define SS ((size_t)S_*(size_t)S_)
#define SH ((size_t)S_*(size_t)H_)
#define NQKV 6912                  // 9 fused weight matrices
#define N3   2304                  // 3 fused weight matrices

typedef __bf16 bf16_t;
typedef __bf16 bf16x8 __attribute__((ext_vector_type(8)));
typedef __bf16 bf16x4 __attribute__((ext_vector_type(4)));
typedef float  f32x4  __attribute__((ext_vector_type(4)));
typedef unsigned short u16;
typedef u16 u16x4 __attribute__((ext_vector_type(4)));
typedef u16 u16x8 __attribute__((ext_vector_type(8)));

typedef __attribute__((address_space(3))) void       lds_void_t;
typedef __attribute__((address_space(1))) const void gvoid_t;

__device__ __forceinline__ float b2f(u16 u){ unsigned x = (unsigned)u << 16; float f; __builtin_memcpy(&f,&x,4); return f; }
__device__ __forceinline__ u16 f2b(float f){ bf16_t h = (bf16_t)f; u16 u; __builtin_memcpy(&u,&h,2); return u; }

template<bool MAXOP>
__device__ __forceinline__ float blockReduce(float v, float* s){
  #pragma unroll
  for (int o = 32; o; o >>= 1){
    float t = __shfl_xor(v, o);
    v = MAXOP ? fmaxf(v, t) : (v + t);
  }
  int lane = threadIdx.x & 63, w = threadIdx.x >> 6;
  if (lane == 0) s[w] = v;
  __syncthreads();
  float r = s[0];
  #pragma unroll
  for (int i = 1; i < 4; i++) r = MAXOP ? fmaxf(r, s[i]) : (r + s[i]);
  __syncthreads();
  return r;
}

__device__ __forceinline__ float waveMax(float v){
  #pragma unroll
  for (int o = 1; o < 64; o <<= 1) v = fmaxf(v, __shfl_xor(v, o));
  return v;
}
__device__ __forceinline__ float waveSum(float v){
  #pragma unroll
  for (int o = 1; o < 64; o <<= 1) v += __shfl_xor(v, o);
  return v;
}

// ---------------- weight conversion fp32 -> bf16; match (proto) plane scaled by 1/sqrt(d) ----------------
struct W18 { const float* p[18]; };

__global__ __launch_bounds__(256) void conv_weights(W18 w, bf16_t* __restrict__ out, float rs){
  int m = blockIdx.y;
  float sc = (m % 3 == 1) ? rs : 1.0f;
  int i = (blockIdx.x * 256 + threadIdx.x) * 4;   // grid.x*1024 == HH exactly
  f32x4 v = *(const f32x4*)(w.p[m] + i);
  bf16x4 o; o[0]=(bf16_t)(v[0]*sc); o[1]=(bf16_t)(v[1]*sc); o[2]=(bf16_t)(v[2]*sc); o[3]=(bf16_t)(v[3]*sc);
  *(bf16x4*)(out + (size_t)m * HH + i) = o;
}

// ---------------- LayerNorm (wave-per-row): fp32 in -> bf16 out ----------------
__global__ __launch_bounds__(256) void ln_kernel(const float* __restrict__ x,
                                                 const float* __restrict__ w,
                                                 const float* __restrict__ b,
                                                 bf16_t* __restrict__ outb){
  int wid = threadIdx.x >> 6, l = threadIdx.x & 63;
  int row = blockIdx.x * 4 + wid;
  size_t base = (size_t)row * H_ + l*12;
  float v[12];
  #pragma unroll
  for (int i = 0; i < 3; i++){
    f32x4 t = *(const f32x4*)(x + base + 4*i);
    #pragma unroll
    for (int j = 0; j < 4; j++) v[4*i+j] = t[j];
  }
  float s1 = 0.f, s2 = 0.f;
  #pragma unroll
  for (int j = 0; j < 12; j++){ s1 += v[j]; s2 += v[j]*v[j]; }
  s1 = waveSum(s1); s2 = waveSum(s2);
  float mu = s1 * (1.f/H_), var = s2 * (1.f/H_) - mu*mu;
  float rstd = rsqrtf(var + 1e-5f);
  #pragma unroll
  for (int i = 0; i < 3; i++){
    f32x4 wv = *(const f32x4*)(w + l*12 + 4*i);
    f32x4 bv = *(const f32x4*)(b + l*12 + 4*i);
    u16x4 u;
    #pragma unroll
    for (int j = 0; j < 4; j++) u[j] = f2b((v[4*i+j]-mu)*rstd*wv[j] + bv[j]);
    *(u16x4*)(outb + base + 4*i) = u;
  }
}

// ====================== 8-phase 256x256 BK=64 GEMM (R9-proven) ======================
template<int MB, int NB>
__device__ __forceinline__ void quad(f32x4 (&acc)[8][4], bf16x8 (&aF)[8][2], bf16x8 (&bF)[4][2]){
  #pragma unroll
  for (int m = MB; m < MB+4; m++)
    #pragma unroll
    for (int n = NB; n < NB+2; n++){
      acc[m][n] = __builtin_amdgcn_mfma_f32_16x16x32_bf16(aF[m][0], bF[n][0], acc[m][n], 0,0,0);
      acc[m][n] = __builtin_amdgcn_mfma_f32_16x16x32_bf16(aF[m][1], bF[n][1], acc[m][n], 0,0,0);
    }
}

__global__ __launch_bounds__(512, 2) void gemm256ph(const bf16_t* __restrict__ A,
                                                    const bf16_t* __restrict__ Bm,
                                                    bf16_t* __restrict__ C,
                                                    int M, int N, int K,
                                                    long sA, long sB, long sC, int causal){
  extern __shared__ char smem[];   // A[2][32KB] | B[2][32KB] = 128 KiB
  char* Ab = smem;
  char* Bb = smem + 65536;

  int bx, by, z;
  if (causal){
    int id = blockIdx.x;
    z = id / 36; int t = id % 36;
    by = 0;
    while ((by+1)*(by+2)/2 <= t) by++;
    bx = t - by*(by+1)/2;
  } else {
    int gx = gridDim.x, gy = gridDim.y;
    int nwg = gx * gy;
    int id  = blockIdx.y * gx + blockIdx.x;
    int cpx = nwg >> 3;
    int nrb = cpx / gx;            // requires cpx % gx == 0
    int x = id & 7; int local = id >> 3;
    bx = local / nrb;
    by = x * nrb + (local % nrb);
    z = 0;
  }

  A  += (size_t)z * sA;
  Bm += (size_t)z * sB;
  C  += (size_t)z * sC;
  int row0 = by * 256, col0 = bx * 256;

  int tid = threadIdx.x, lane = tid & 63, wid = tid >> 6;
  int wm = wid >> 2, wn = wid & 3;        // 2x4 waves, 128x64 out each
  int lr = lane & 15, kg = lane >> 4;
  int NT = K >> 6;                         // BK = 64

  auto stA = [&](int buf, int h, int kt){
    #pragma unroll
    for (int i = 0; i < 2; i++){
      int cc = tid + i*512;
      int rl = cc >> 3, sl = cc & 7;
      const bf16_t* src = A + (size_t)(row0 + h*128 + rl)*K + kt*64 + (sl ^ (rl & 7))*8;
      char* dst = Ab + buf*32768 + h*16384 + cc*16;
      __builtin_amdgcn_global_load_lds((gvoid_t*)src, (lds_void_t*)dst, 16, 0, 0);
    }
  };
  auto stB = [&](int buf, int h, int kt){
    #pragma unroll
    for (int i = 0; i < 2; i++){
      int cc = tid + i*512;
      int rl = cc >> 3, sl = cc & 7;
      const bf16_t* src = Bm + (size_t)(col0 + h*128 + rl)*K + kt*64 + (sl ^ (rl & 7))*8;
      char* dst = Bb + buf*32768 + h*16384 + cc*16;
      __builtin_amdgcn_global_load_lds((gvoid_t*)src, (lds_void_t*)dst, 16, 0, 0);
    }
  };
  auto rd = [&](char* base, int buf, int r, int kh) -> bf16x8 {
    return *(const bf16x8*)(base + buf*32768 + r*128 + (((kh<<2)+kg) ^ (r & 7))*16);
  };

  f32x4 acc[8][4] = {};
  bf16x8 aF[8][2], bF[4][2];

  stA(0,0,0); stA(0,1,0); stB(0,0,0); stB(0,1,0);
  if (NT > 1){ stB(1,0,1); stB(1,1,1);
    asm volatile("s_waitcnt vmcnt(4)" ::: "memory");
  } else {
    asm volatile("s_waitcnt vmcnt(0)" ::: "memory");
  }
  __builtin_amdgcn_s_barrier();

  int buf = 0;
  for (int t = 0; t < NT; ++t){
    int nb = buf ^ 1;
    // ---- phase 0 ----
    #pragma unroll
    for (int m = 0; m < 4; m++){ int r = wm*128 + m*16 + lr;
      aF[m][0] = rd(Ab, buf, r, 0); aF[m][1] = rd(Ab, buf, r, 1); }
    #pragma unroll
    for (int n = 0; n < 2; n++){ int r = wn*64 + n*16 + lr;
      bF[n][0] = rd(Bb, buf, r, 0); bF[n][1] = rd(Bb, buf, r, 1); }
    if (t + 1 < NT) stA(nb, 0, t+1);
    __builtin_amdgcn_s_barrier();
    asm volatile("s_waitcnt lgkmcnt(0)" ::: "memory");
    __builtin_amdgcn_sched_barrier(0);
    __builtin_amdgcn_s_setprio(1);
    quad<0,0>(acc, aF, bF);
    __builtin_amdgcn_s_setprio(0);
    __builtin_amdgcn_s_barrier();
    // ---- phase 1 ----
    #pragma unroll
    for (int n = 2; n < 4; n++){ int r = wn*64 + n*16 + lr;
      bF[n][0] = rd(Bb, buf, r, 0); bF[n][1] = rd(Bb, buf, r, 1); }
    if (t + 1 < NT) stA(nb, 1, t+1);
    __builtin_amdgcn_s_barrier();
    asm volatile("s_waitcnt lgkmcnt(0)" ::: "memory");
    __builtin_amdgcn_sched_barrier(0);
    __builtin_amdgcn_s_setprio(1);
    quad<0,2>(acc, aF, bF);
    __builtin_amdgcn_s_setprio(0);
    __builtin_amdgcn_s_barrier();
    // ---- phase 2 ----
    #pragma unroll
    for (int m = 4; m < 8; m++){ int r = wm*128 + m*16 + lr;
      aF[m][0] = rd(Ab, buf, r, 0); aF[m][1] = rd(Ab, buf, r, 1); }
    if (t + 2 < NT) stB(buf, 0, t+2);
    __builtin_amdgcn_s_barrier();
    asm volatile("s_waitcnt lgkmcnt(0)" ::: "memory");
    __builtin_amdgcn_sched_barrier(0);
    __builtin_amdgcn_s_setprio(1);
    quad<4,0>(acc, aF, bF);
    __builtin_amdgcn_s_setprio(0);
    __builtin_amdgcn_s_barrier();
    // ---- phase 3 ----
    if (t + 2 < NT) stB(buf, 1, t+2);
    __builtin_amdgcn_s_barrier();
    __builtin_amdgcn_s_setprio(1);
    quad<4,2>(acc, aF, bF);
    __builtin_amdgcn_s_setprio(0);
    if (t + 2 < NT)      asm volatile("s_waitcnt vmcnt(4)" ::: "memory");
    else if (t + 1 < NT) asm volatile("s_waitcnt vmcnt(0)" ::: "memory");
    __builtin_amdgcn_s_barrier();
    buf = nb;
  }

  // epilogue: C/D layout col=lane&15, row=(lane>>4)*4+reg
  #pragma unroll
  for (int m = 0; m < 8; m++){
    int rb = row0 + wm*128 + m*16 + kg*4;
    #pragma unroll
    for (int n = 0; n < 4; n++){
      int cc = col0 + wn*64 + n*16 + lr;
      #pragma unroll
      for (int r = 0; r < 4; r++)
        C[(size_t)(rb + r)*N + cc] = (bf16_t)acc[m][n][r];
    }
  }
}

// ======================================================================
// 128x128 GEMM, ring-3 LDS, counted vmcnt (R6-proven). XOR swizzle
// (r>>1)&3. cmode: 0 XCD-band mapping; 1 triangle-compacted causal grid
// (grid = (136,1,B)); 2 causal K-limit (XCD-band mapping).
// ======================================================================
__global__ __launch_bounds__(256) void gemm_bt(const bf16_t* __restrict__ A,
                                               const bf16_t* __restrict__ Bm,
                                               bf16_t* __restrict__ C,
                                               int M, int N, int K,
                                               long sA, long sB, long sC, int cmode){
  __shared__ bf16_t As[3][128*32];
  __shared__ bf16_t Bs[3][128*32];

  int bx, by, z;
  if (cmode == 1){
    z = blockIdx.z;
    int t = blockIdx.x;            // 0..135, lower-triangle incl diagonal
    by = 0;
    while ((by+1)*(by+2)/2 <= t) by++;
    bx = t - by*(by+1)/2;
  } else {
    int gx = gridDim.x, gy = gridDim.y;
    int nwg = gx * gy * gridDim.z;
    int id  = (blockIdx.z * gy + blockIdx.y) * gx + blockIdx.x;
    int cpx = nwg >> 3;
    int nrb = cpx / gx;
    int x   = id & 7;
    int local = id >> 3;
    bx  = local / nrb;
    int frow = x * nrb + (local % nrb);
    by  = frow % gy;
    z   = frow / gy;
  }

  A  += (size_t)z * sA;
  Bm += (size_t)z * sB;
  C  += (size_t)z * sC;

  int row0 = by * 128, col0 = bx * 128;

  int tid  = threadIdx.x;
  int lane = tid & 63;
  int wave = tid >> 6;
  int wm = wave >> 1, wn = wave & 1;
  int lr = lane & 15, kg = lane >> 4;

  f32x4 acc[4][4] = {};
  int NT = K >> 5;
  if (cmode == 2) { int lim = (row0 + 128) >> 5; NT = NT < lim ? NT : lim; }

  auto stage = [&](int buf, int kt){
    int kk = kt * 32;
    #pragma unroll
    for (int i = 0; i < 2; i++){
      int c  = tid + i*256;
      int r  = c >> 2;
      int scol = ((c & 3) ^ ((r >> 1) & 3)) * 8;
      __builtin_amdgcn_global_load_lds((gvoid_t*)(A  + (size_t)(row0 + r)*K + kk + scol),
                                       (lds_void_t*)(&As[buf][c*8]), 16, 0, 0);
      __builtin_amdgcn_global_load_lds((gvoid_t*)(Bm + (size_t)(col0 + r)*K + kk + scol),
                                       (lds_void_t*)(&Bs[buf][c*8]), 16, 0, 0);
    }
  };

  stage(0, 0);
  stage(1, 1);                                  // NT >= 2 for all our calls
  asm volatile("s_waitcnt vmcnt(4)" ::: "memory");
  __builtin_amdgcn_s_barrier();
  __builtin_amdgcn_sched_barrier(0);

  int b0 = 0, b1 = 1, b2 = 2;
  for (int kt = 0; kt < NT; ++kt){
    if (kt + 2 < NT) stage(b2, kt + 2);
    bf16x8 af[4], bfr[4];
    #pragma unroll
    for (int m = 0; m < 4; m++){
      int r = wm*64 + m*16 + lr;
      af[m] = *reinterpret_cast<const bf16x8*>(&As[b0][r*32 + ((kg ^ ((r >> 1) & 3)) * 8)]);
    }
    #pragma unroll
    for (int n = 0; n < 4; n++){
      int r = wn*64 + n*16 + lr;
      bfr[n] = *reinterpret_cast<const bf16x8*>(&Bs[b0][r*32 + ((kg ^ ((r >> 1) & 3)) * 8)]);
    }
    #pragma unroll
    for (int m = 0; m < 4; m++)
      #pragma unroll
      for (int n = 0; n < 4; n++)
        acc[m][n] = __builtin_amdgcn_mfma_f32_16x16x32_bf16(af[m], bfr[n], acc[m][n], 0, 0, 0);
    if (kt + 1 < NT){
      if (kt + 2 < NT) asm volatile("s_waitcnt vmcnt(4)" ::: "memory");
      else             asm volatile("s_waitcnt vmcnt(0)" ::: "memory");
      __builtin_amdgcn_s_barrier();
      __builtin_amdgcn_sched_barrier(0);
    }
    int tmp = b0; b0 = b1; b1 = b2; b2 = tmp;
  }

  #pragma unroll
  for (int m = 0; m < 4; m++){
    int rb = row0 + wm*64 + m*16 + kg*4;
    #pragma unroll
    for (int n = 0; n < 4; n++){
      int cc = col0 + wn*64 + n*16 + lr;
      #pragma unroll
      for (int r = 0; r < 4; r++)
        C[(size_t)(rb + r)*N + cc] = (bf16_t)acc[m][n][r];
    }
  }
}

// ---------------- merged QKV gate: wave-per-row, 3 sections ----------------
__global__ __launch_bounds__(256) void gate_qkv(const bf16_t* __restrict__ inp,
                                                const bf16_t* __restrict__ c3,
                                                const float* __restrict__ b_q,
                                                const float* __restrict__ b_k,
                                                const float* __restrict__ b_v,
                                                const float* __restrict__ cosT,
                                                const float* __restrict__ sinT,
                                                bf16_t* __restrict__ q_o,
                                                bf16_t* __restrict__ k_o,
                                                bf16_t* __restrict__ v_o,
                                                float rs){
  int wid = threadIdx.x >> 6, l = threadIdx.x & 63;
  int row = blockIdx.x * 4 + wid;
  size_t bi = (size_t)row * H_ + l*12;
  size_t brow = (size_t)row * NQKV + l*12;

  float iv[12];
  #pragma unroll
  for (int i = 0; i < 3; i++){
    u16x4 a = *(const u16x4*)(inp + bi + 4*i);
    #pragma unroll
    for (int j = 0; j < 4; j++) iv[4*i+j] = b2f(a[j]);
  }
  int s = row & (S_ - 1);
  f32x4 cw[3], sw[3];
  #pragma unroll
  for (int i = 0; i < 3; i++){
    cw[i] = *(const f32x4*)(cosT + (size_t)s*H_ + l*12 + 4*i);
    sw[i] = *(const f32x4*)(sinT + (size_t)s*H_ + l*12 + 4*i);
  }

  const float* biasp[3] = {b_q, b_k, b_v};
  bf16_t* outp[3] = {q_o, k_o, v_o};

  #pragma unroll
  for (int sec = 0; sec < 3; sec++){
    size_t bc = brow + (size_t)sec * 2304;
    float cv[12], mv[12], gv[12];
    float gmax = 0.f;
    #pragma unroll
    for (int i = 0; i < 3; i++){
      u16x4 b = *(const u16x4*)(c3 + bc + 4*i);
      u16x4 c = *(const u16x4*)(c3 + bc + 768 + 4*i);
      u16x4 d = *(const u16x4*)(c3 + bc + 1536 + 4*i);
      f32x4 bv = *(const f32x4*)(biasp[sec] + l*12 + 4*i);
      #pragma unroll
      for (int j = 0; j < 4; j++){
        cv[4*i+j] = b2f(b[j]) + bv[j];
        mv[4*i+j] = b2f(c[j]);
        gv[4*i+j] = b2f(d[j]);
        gmax = fmaxf(gmax, fabsf(gv[4*i+j]));
      }
    }
    gmax = waveMax(gmax);
    float rg = 1.f / (gmax + 1e-9f);
    float rt[12], rmax = 0.f;
    #pragma unroll
    for (int j = 0; j < 12; j++){
      rt[j] = mv[j] - fmaxf(gv[j]*rg, 0.f);
      rmax  = fmaxf(rmax, fabsf(rt[j]));
    }
    rmax = waveMax(rmax);
    float rr = 1.f / (rmax + 1e-9f);
    float oscale = (sec == 0) ? rs : 1.0f;
    float val[12];
    #pragma unroll
    for (int j = 0; j < 12; j++) val[j] = (iv[j] + cv[j]) * fmaxf(rt[j]*rr, 0.f) * oscale;

    if (sec < 2){
      #pragma unroll
      for (int i = 0; i < 3; i++){
        u16x4 u;
        #pragma unroll
        for (int j = 0; j < 4; j++){
          int q = 4*i + j;
          float partner = __shfl_xor(val[q], 32);
          if (l < 32) partner = -partner;
          u[j] = f2b(val[q]*cw[i][j] + partner*sw[i][j]);
        }
        *(u16x4*)(outp[sec] + bi + 4*i) = u;
      }
    } else {
      #pragma unroll
      for (int i = 0; i < 3; i++){
        u16x4 u;
        #pragma unroll
        for (int j = 0; j < 4; j++) u[j] = f2b(val[4*i+j]);
        *(u16x4*)(outp[sec] + bi + 4*i) = u;
      }
    }
  }
}

// ---------------- gate branch: wave-per-row ----------------
// mode 2: +resid -> outf ; 3: relu -> outb ; 4: +resid -> outf AND LN -> outb
__global__ __launch_bounds__(256) void gate_kernel(const bf16_t* __restrict__ inp,
                                                   const bf16_t* __restrict__ c3,
                                                   long ldc, int colbase,
                                                   const float* __restrict__ bias,
                                                   const float* __restrict__ resid,
                                                   const float* __restrict__ lnw,
                                                   const float* __restrict__ lnb,
                                                   float* __restrict__ outf,
                                                   bf16_t* __restrict__ outb,
                                                   int mode){
  int wid = threadIdx.x >> 6, l = threadIdx.x & 63;
  int row = blockIdx.x * 4 + wid;
  size_t bi = (size_t)row * H_ + l*12;
  size_t bc = (size_t)row * ldc + colbase + l*12;

  float iv[12], cv[12], mv[12], gv[12];
  float gmax = 0.f;
  #pragma unroll
  for (int i = 0; i < 3; i++){
    u16x4 a = *(const u16x4*)(inp + bi + 4*i);
    u16x4 b = *(const u16x4*)(c3 + bc + 4*i);
    u16x4 c = *(const u16x4*)(c3 + bc + 768 + 4*i);
    u16x4 d = *(const u16x4*)(c3 + bc + 1536 + 4*i);
    f32x4 bv = *(const f32x4*)(bias + l*12 + 4*i);
    #pragma unroll
    for (int j = 0; j < 4; j++){
      iv[4*i+j] = b2f(a[j]); cv[4*i+j] = b2f(b[j]) + bv[j];
      mv[4*i+j] = b2f(c[j]); gv[4*i+j] = b2f(d[j]);
      gmax = fmaxf(gmax, fabsf(gv[4*i+j]));
    }
  }
  gmax = waveMax(gmax);
  float rg = 1.f / (gmax + 1e-9f);

  float rt[12], rmax = 0.f;
  #pragma unroll
  for (int j = 0; j < 12; j++){
    rt[j] = mv[j] - fmaxf(gv[j]*rg, 0.f);
    rmax  = fmaxf(rmax, fabsf(rt[j]));
  }
  rmax = waveMax(rmax);
  float rr = 1.f / (rmax + 1e-9f);

  float val[12];
  #pragma unroll
  for (int j = 0; j < 12; j++) val[j] = (iv[j] + cv[j]) * fmaxf(rt[j]*rr, 0.f);

  if (mode == 3){
    #pragma unroll
    for (int i = 0; i < 3; i++){
      u16x4 u;
      #pragma unroll
      for (int j = 0; j < 4; j++) u[j] = f2b(fmaxf(val[4*i+j], 0.f));
      *(u16x4*)(outb + bi + 4*i) = u;
    }
  } else if (mode == 2){
    #pragma unroll
    for (int i = 0; i < 3; i++){
      f32x4 rv = *(const f32x4*)(resid + bi + 4*i);
      f32x4 ov;
      #pragma unroll
      for (int j = 0; j < 4; j++) ov[j] = val[4*i+j] + rv[j];
      *(f32x4*)(outf + bi + 4*i) = ov;
    }
  } else { // mode 4
    float xv[12];
    #pragma unroll
    for (int i = 0; i < 3; i++){
      f32x4 rv = *(const f32x4*)(resid + bi + 4*i);
      f32x4 ov;
      #pragma unroll
      for (int j = 0; j < 4; j++){ xv[4*i+j] = val[4*i+j] + rv[j]; ov[j] = xv[4*i+j]; }
      *(f32x4*)(outf + bi + 4*i) = ov;
    }
    float s1 = 0.f, s2 = 0.f;
    #pragma unroll
    for (int j = 0; j < 12; j++){ s1 += xv[j]; s2 += xv[j]*xv[j]; }
    s1 = waveSum(s1); s2 = waveSum(s2);
    float mu = s1 * (1.f/H_), var = s2 * (1.f/H_) - mu*mu;
    float rstd = rsqrtf(var + 1e-5f);
    #pragma unroll
    for (int i = 0; i < 3; i++){
      f32x4 wv = *(const f32x4*)(lnw + l*12 + 4*i);
      f32x4 bv = *(const f32x4*)(lnb + l*12 + 4*i);
      u16x4 u;
      #pragma unroll
      for (int j = 0; j < 4; j++) u[j] = f2b((xv[4*i+j]-mu)*rstd*wv[j] + bv[j]);
      *(u16x4*)(outb + bi + 4*i) = u;
    }
  }
}

// ---------------- single-pass causal softmax: 8 cols/thread in registers ----------------
__global__ __launch_bounds__(256) void softmax_causal(const bf16_t* __restrict__ sc,
                                                      bf16_t* __restrict__ P){
  __shared__ float red[4];
  int r = blockIdx.x, b = blockIdx.y, t = threadIdx.x;
  const bf16_t* srow = sc + (size_t)b*SS + (size_t)r * S_;
  bf16_t* prow = P + (size_t)b*SS + (size_t)r * S_;
  int n = r + 1;
  int fill = ((r >> 7) + 1) << 7;          // PV reads k < row0+128; zero up to there
  int c0 = t * 8;

  float v[8];
  float m = -1e30f;
  if (c0 < n){
    u16x8 u = *(const u16x8*)(srow + c0);
    #pragma unroll
    for (int j = 0; j < 8; j++){
      v[j] = (c0 + j < n) ? b2f(u[j]) : -1e30f;
      m = fmaxf(m, v[j]);
    }
  } else {
    #pragma unroll
    for (int j = 0; j < 8; j++) v[j] = -1e30f;
  }
  m = blockReduce<true>(m, red);
  float sum = 0.f;
  #pragma unroll
  for (int j = 0; j < 8; j++){
    v[j] = (v[j] > -1e29f) ? __expf(v[j] - m) : 0.f;
    sum += v[j];
  }
  sum = blockReduce<false>(sum, red);
  float inv = 1.f / sum;
  if (c0 < fill){
    u16x8 u;
    #pragma unroll
    for (int j = 0; j < 8; j++) u[j] = f2b(v[j] * inv);
    *(u16x8*)(prow + c0) = u;
  }
}

// ---------------- 32x32 tiled transpose [B,S,H] -> [B,H,S] ----------------
__global__ __launch_bounds__(256) void transpose_bf(const bf16_t* __restrict__ in,
                                                    bf16_t* __restrict__ out){
  __shared__ bf16_t tile[32][33];
  int bz = blockIdx.z;
  const bf16_t* I = in  + (size_t)bz * SH;
  bf16_t*       O = out + (size_t)bz * SH;
  int s0 = blockIdx.x*32, h0 = blockIdx.y*32;
  int tx = threadIdx.x, ty = threadIdx.y;
  #pragma unroll
  for (int k = 0; k < 4; k++)
    tile[ty + 8*k][tx] = I[(size_t)(s0 + ty + 8*k)*H_ + h0 + tx];
  __syncthreads();
  #pragma unroll
  for (int k = 0; k < 4; k++)
    O[(size_t)(h0 + ty + 8*k)*S_ + s0 + tx] = tile[tx][ty + 8*k];
}

// ---------------- launch ----------------
extern "C" void kernel_launch(void* const* d_in, const int* in_sizes, int n_in,
                              void* d_out, int out_size, void* d_ws, size_t ws_size,
                              hipStream_t stream){
  const float* x    = (const float*)d_in[0];
  const float* cosT = (const float*)d_in[1];
  const float* sinT = (const float*)d_in[2];
  const float* ln1w = (const float*)d_in[3];
  const float* ln1b = (const float*)d_in[4];
  const float* ln2w = (const float*)d_in[5];
  const float* ln2b = (const float*)d_in[6];

  W18 wp; const float* bias[6];
  for (int i = 0; i < 6; i++){
    const float* proto = (const float*)d_in[7 + 4*i + 0];
    const float* gatep = (const float*)d_in[7 + 4*i + 1];
    const float* muw   = (const float*)d_in[7 + 4*i + 2];
    bias[i]            = (const float*)d_in[7 + 4*i + 3];
    wp.p[i*3 + 0] = muw;    // comp
    wp.p[i*3 + 1] = proto;  // match (scaled by rs at conversion)
    wp.p[i*3 + 2] = gatep;  // gate
  }

  hipFuncSetAttribute((const void*)gemm256ph, hipFuncAttributeMaxDynamicSharedMemorySize, 131072);

  char* w = (char*)d_ws;
  auto alloc = [&](size_t bytes){ void* r = (void*)w; w += (bytes + 255) & ~(size_t)255; return r; };
  bf16_t* w_bf   = (bf16_t*)alloc((size_t)18 * HH * 2);      // [13824, 768]
  bf16_t* a_bf   = (bf16_t*)alloc(MN * 2);
  bf16_t* h_bf   = (bf16_t*)alloc(MN * 2);
  bf16_t* c3b    = (bf16_t*)alloc((size_t)M_ * NQKV * 2);    // logits; overlays scores+P
  bf16_t* q_bf   = (bf16_t*)alloc(MN * 2);
  bf16_t* k_bf   = (bf16_t*)alloc(MN * 2);
  bf16_t* v_bf   = (bf16_t*)alloc(MN * 2);
  bf16_t* vt     = (bf16_t*)alloc(MN * 2);
  bf16_t* attn_b = (bf16_t*)alloc(MN * 2);
  float*  x1     = (float*) alloc(MN * 4);
  (void)ws_size;
  bf16_t* sc_bf = c3b;
  bf16_t* p_bf  = c3b + B_ * SS;

  const float rs = 1.0f / sqrtf((float)H_);

  conv_weights<<<dim3(HH/1024, 18), 256, 0, stream>>>(wp, w_bf, rs);
  ln_kernel<<<M_/4, 256, 0, stream>>>(x, ln1w, ln1b, a_bf);

  // QKV fused SPL: c3b[M, 6912]  — 8-phase 256^2 BK=64 kernel (R9 config)
  gemm256ph<<<dim3(NQKV/256, M_/256, 1), 512, 131072, stream>>>(
      a_bf, w_bf, c3b, M_, NQKV, H_, 0, 0, 0, 0);
  gate_qkv<<<M_/4, 256, 0, stream>>>(a_bf, c3b, bias[0], bias[1], bias[2],
                                     cosT, sinT, q_bf, k_bf, v_bf, rs);

  transpose_bf<<<dim3(S_/32, H_/32, B_), dim3(32, 8), 0, stream>>>(v_bf, vt);

  // QK^T (scale folded into q) — ring-3 128^2, triangle-compacted grid
  gemm_bt<<<dim3(136, 1, B_), 256, 0, stream>>>(
      q_bf, k_bf, sc_bf, S_, S_, H_, (long)SH, (long)SH, (long)SS, 1);

  softmax_causal<<<dim3(S_, B_), 256, 0, stream>>>(sc_bf, p_bf);

  // PV (K limited causally) — ring-3 128^2
  gemm_bt<<<dim3(H_/128, S_/128, B_), 256, 0, stream>>>(
      p_bf, vt, attn_b, S_, H_, S_, (long)SS, (long)SH, (long)SH, 2);

  // o-SPL + gate(+residual x) + fused LN2 -> x1 and a_bf
  gemm_bt<<<dim3(N3/128, M_/128, 1), 256, 0, stream>>>(
      attn_b, w_bf + (size_t)9*HH, c3b, M_, N3, H_, 0, 0, 0, 0);
  gate_kernel<<<M_/4, 256, 0, stream>>>(attn_b, c3b, N3, 0, bias[3], x, ln2w, ln2b, x1, a_bf, 4);

  // f1-SPL + gate + relu -> h_bf
  gemm_bt<<<dim3(N3/128, M_/128, 1), 256, 0, stream>>>(
      a_bf, w_bf + (size_t)12*HH, c3b, M_, N3, H_, 0, 0, 0, 0);
  gate_kernel<<<M_/4, 256, 0, stream>>>(a_bf, c3b, N3, 0, bias[4], nullptr, nullptr, nullptr, nullptr, h_bf, 3);

  // f2-SPL + gate(+residual x1) -> d_out
  gemm_bt<<<dim3(N3/128, M_/128, 1), 256, 0, stream>>>(
      h_bf, w_bf + (size_t)15*HH, c3b, M_, N3, H_, 0, 0, 0, 0);
  gate_kernel<<<M_/4, 256, 0, stream>>>(h_bf, c3b, N3, 0, bias[5], x1, nullptr, nullptr, (float*)d_out, nullptr, 2);
}

// Round 12
// 421.126 us; speedup vs baseline: 1.0460x; 1.0403x over previous
//
#include <hip/hip_runtime.h>
#include <hip/hip_bf16.h>
#include <math.h>

#define B_ 4
#define S_ 2048
#define H_ 768
#define M_ (B_*S_)                 // 8192 rows
#define MN ((size_t)M_*(size_t)H_) // 6291456
#define HH (H_*H_)                 // 589824
#define SS ((size_t)S_*(size_t)S_)
#define SH ((size_t)S_*(size_t)H_)
#define NQKV 6912                  // 9 fused weight matrices
#define N3   2304                  // 3 fused weight matrices

typedef __bf16 bf16_t;
typedef __bf16 bf16x8 __attribute__((ext_vector_type(8)));
typedef __bf16 bf16x4 __attribute__((ext_vector_type(4)));
typedef float  f32x4  __attribute__((ext_vector_type(4)));
typedef unsigned short u16;
typedef u16 u16x4 __attribute__((ext_vector_type(4)));
typedef u16 u16x8 __attribute__((ext_vector_type(8)));

typedef __attribute__((address_space(3))) void       lds_void_t;
typedef __attribute__((address_space(1))) const void gvoid_t;

__device__ __forceinline__ float b2f(u16 u){ unsigned x = (unsigned)u << 16; float f; __builtin_memcpy(&f,&x,4); return f; }
__device__ __forceinline__ u16 f2b(float f){ bf16_t h = (bf16_t)f; u16 u; __builtin_memcpy(&u,&h,2); return u; }

template<bool MAXOP>
__device__ __forceinline__ float blockReduce(float v, float* s){
  #pragma unroll
  for (int o = 32; o; o >>= 1){
    float t = __shfl_xor(v, o);
    v = MAXOP ? fmaxf(v, t) : (v + t);
  }
  int lane = threadIdx.x & 63, w = threadIdx.x >> 6;
  if (lane == 0) s[w] = v;
  __syncthreads();
  float r = s[0];
  #pragma unroll
  for (int i = 1; i < 4; i++) r = MAXOP ? fmaxf(r, s[i]) : (r + s[i]);
  __syncthreads();
  return r;
}

__device__ __forceinline__ float waveMax(float v){
  #pragma unroll
  for (int o = 1; o < 64; o <<= 1) v = fmaxf(v, __shfl_xor(v, o));
  return v;
}
__device__ __forceinline__ float waveSum(float v){
  #pragma unroll
  for (int o = 1; o < 64; o <<= 1) v += __shfl_xor(v, o);
  return v;
}

// ---------------- weight conversion fp32 -> bf16; match (proto) plane scaled by 1/sqrt(d) ----------------
struct W18 { const float* p[18]; };

__global__ __launch_bounds__(256) void conv_weights(W18 w, bf16_t* __restrict__ out, float rs){
  int m = blockIdx.y;
  float sc = (m % 3 == 1) ? rs : 1.0f;
  int i = (blockIdx.x * 256 + threadIdx.x) * 4;   // grid.x*1024 == HH exactly
  f32x4 v = *(const f32x4*)(w.p[m] + i);
  bf16x4 o; o[0]=(bf16_t)(v[0]*sc); o[1]=(bf16_t)(v[1]*sc); o[2]=(bf16_t)(v[2]*sc); o[3]=(bf16_t)(v[3]*sc);
  *(bf16x4*)(out + (size_t)m * HH + i) = o;
}

// ---------------- LayerNorm (wave-per-row): fp32 in -> bf16 out ----------------
__global__ __launch_bounds__(256) void ln_kernel(const float* __restrict__ x,
                                                 const float* __restrict__ w,
                                                 const float* __restrict__ b,
                                                 bf16_t* __restrict__ outb){
  int wid = threadIdx.x >> 6, l = threadIdx.x & 63;
  int row = blockIdx.x * 4 + wid;
  size_t base = (size_t)row * H_ + l*12;
  float v[12];
  #pragma unroll
  for (int i = 0; i < 3; i++){
    f32x4 t = *(const f32x4*)(x + base + 4*i);
    #pragma unroll
    for (int j = 0; j < 4; j++) v[4*i+j] = t[j];
  }
  float s1 = 0.f, s2 = 0.f;
  #pragma unroll
  for (int j = 0; j < 12; j++){ s1 += v[j]; s2 += v[j]*v[j]; }
  s1 = waveSum(s1); s2 = waveSum(s2);
  float mu = s1 * (1.f/H_), var = s2 * (1.f/H_) - mu*mu;
  float rstd = rsqrtf(var + 1e-5f);
  #pragma unroll
  for (int i = 0; i < 3; i++){
    f32x4 wv = *(const f32x4*)(w + l*12 + 4*i);
    f32x4 bv = *(const f32x4*)(b + l*12 + 4*i);
    u16x4 u;
    #pragma unroll
    for (int j = 0; j < 4; j++) u[j] = f2b((v[4*i+j]-mu)*rstd*wv[j] + bv[j]);
    *(u16x4*)(outb + base + 4*i) = u;
  }
}

// ====================== 8-phase 256x256 BK=64 GEMM (R9-proven) ======================
template<int MB, int NB>
__device__ __forceinline__ void quad(f32x4 (&acc)[8][4], bf16x8 (&aF)[8][2], bf16x8 (&bF)[4][2]){
  #pragma unroll
  for (int m = MB; m < MB+4; m++)
    #pragma unroll
    for (int n = NB; n < NB+2; n++){
      acc[m][n] = __builtin_amdgcn_mfma_f32_16x16x32_bf16(aF[m][0], bF[n][0], acc[m][n], 0,0,0);
      acc[m][n] = __builtin_amdgcn_mfma_f32_16x16x32_bf16(aF[m][1], bF[n][1], acc[m][n], 0,0,0);
    }
}

__global__ __launch_bounds__(512, 2) void gemm256ph(const bf16_t* __restrict__ A,
                                                    const bf16_t* __restrict__ Bm,
                                                    bf16_t* __restrict__ C,
                                                    int M, int N, int K,
                                                    long sA, long sB, long sC, int causal){
  extern __shared__ char smem[];   // A[2][32KB] | B[2][32KB] = 128 KiB
  char* Ab = smem;
  char* Bb = smem + 65536;

  int bx, by, z;
  if (causal){
    int id = blockIdx.x;
    z = id / 36; int t = id % 36;
    by = 0;
    while ((by+1)*(by+2)/2 <= t) by++;
    bx = t - by*(by+1)/2;
  } else {
    int gx = gridDim.x, gy = gridDim.y;
    int nwg = gx * gy;
    int id  = blockIdx.y * gx + blockIdx.x;
    int cpx = nwg >> 3;
    int nrb = cpx / gx;            // requires cpx % gx == 0
    int x = id & 7; int local = id >> 3;
    bx = local / nrb;
    by = x * nrb + (local % nrb);
    z = 0;
  }

  A  += (size_t)z * sA;
  Bm += (size_t)z * sB;
  C  += (size_t)z * sC;
  int row0 = by * 256, col0 = bx * 256;

  int tid = threadIdx.x, lane = tid & 63, wid = tid >> 6;
  int wm = wid >> 2, wn = wid & 3;        // 2x4 waves, 128x64 out each
  int lr = lane & 15, kg = lane >> 4;
  int NT = K >> 6;                         // BK = 64

  auto stA = [&](int buf, int h, int kt){
    #pragma unroll
    for (int i = 0; i < 2; i++){
      int cc = tid + i*512;
      int rl = cc >> 3, sl = cc & 7;
      const bf16_t* src = A + (size_t)(row0 + h*128 + rl)*K + kt*64 + (sl ^ (rl & 7))*8;
      char* dst = Ab + buf*32768 + h*16384 + cc*16;
      __builtin_amdgcn_global_load_lds((gvoid_t*)src, (lds_void_t*)dst, 16, 0, 0);
    }
  };
  auto stB = [&](int buf, int h, int kt){
    #pragma unroll
    for (int i = 0; i < 2; i++){
      int cc = tid + i*512;
      int rl = cc >> 3, sl = cc & 7;
      const bf16_t* src = Bm + (size_t)(col0 + h*128 + rl)*K + kt*64 + (sl ^ (rl & 7))*8;
      char* dst = Bb + buf*32768 + h*16384 + cc*16;
      __builtin_amdgcn_global_load_lds((gvoid_t*)src, (lds_void_t*)dst, 16, 0, 0);
    }
  };
  auto rd = [&](char* base, int buf, int r, int kh) -> bf16x8 {
    return *(const bf16x8*)(base + buf*32768 + r*128 + (((kh<<2)+kg) ^ (r & 7))*16);
  };

  f32x4 acc[8][4] = {};
  bf16x8 aF[8][2], bF[4][2];

  stA(0,0,0); stA(0,1,0); stB(0,0,0); stB(0,1,0);
  if (NT > 1){ stB(1,0,1); stB(1,1,1);
    asm volatile("s_waitcnt vmcnt(4)" ::: "memory");
  } else {
    asm volatile("s_waitcnt vmcnt(0)" ::: "memory");
  }
  __builtin_amdgcn_s_barrier();

  int buf = 0;
  for (int t = 0; t < NT; ++t){
    int nb = buf ^ 1;
    // ---- phase 0 ----
    #pragma unroll
    for (int m = 0; m < 4; m++){ int r = wm*128 + m*16 + lr;
      aF[m][0] = rd(Ab, buf, r, 0); aF[m][1] = rd(Ab, buf, r, 1); }
    #pragma unroll
    for (int n = 0; n < 2; n++){ int r = wn*64 + n*16 + lr;
      bF[n][0] = rd(Bb, buf, r, 0); bF[n][1] = rd(Bb, buf, r, 1); }
    if (t + 1 < NT) stA(nb, 0, t+1);
    __builtin_amdgcn_s_barrier();
    asm volatile("s_waitcnt lgkmcnt(0)" ::: "memory");
    __builtin_amdgcn_sched_barrier(0);
    __builtin_amdgcn_s_setprio(1);
    quad<0,0>(acc, aF, bF);
    __builtin_amdgcn_s_setprio(0);
    __builtin_amdgcn_s_barrier();
    // ---- phase 1 ----
    #pragma unroll
    for (int n = 2; n < 4; n++){ int r = wn*64 + n*16 + lr;
      bF[n][0] = rd(Bb, buf, r, 0); bF[n][1] = rd(Bb, buf, r, 1); }
    if (t + 1 < NT) stA(nb, 1, t+1);
    __builtin_amdgcn_s_barrier();
    asm volatile("s_waitcnt lgkmcnt(0)" ::: "memory");
    __builtin_amdgcn_sched_barrier(0);
    __builtin_amdgcn_s_setprio(1);
    quad<0,2>(acc, aF, bF);
    __builtin_amdgcn_s_setprio(0);
    __builtin_amdgcn_s_barrier();
    // ---- phase 2 ----
    #pragma unroll
    for (int m = 4; m < 8; m++){ int r = wm*128 + m*16 + lr;
      aF[m][0] = rd(Ab, buf, r, 0); aF[m][1] = rd(Ab, buf, r, 1); }
    if (t + 2 < NT) stB(buf, 0, t+2);
    __builtin_amdgcn_s_barrier();
    asm volatile("s_waitcnt lgkmcnt(0)" ::: "memory");
    __builtin_amdgcn_sched_barrier(0);
    __builtin_amdgcn_s_setprio(1);
    quad<4,0>(acc, aF, bF);
    __builtin_amdgcn_s_setprio(0);
    __builtin_amdgcn_s_barrier();
    // ---- phase 3 ----
    if (t + 2 < NT) stB(buf, 1, t+2);
    __builtin_amdgcn_s_barrier();
    __builtin_amdgcn_s_setprio(1);
    quad<4,2>(acc, aF, bF);
    __builtin_amdgcn_s_setprio(0);
    if (t + 2 < NT)      asm volatile("s_waitcnt vmcnt(4)" ::: "memory");
    else if (t + 1 < NT) asm volatile("s_waitcnt vmcnt(0)" ::: "memory");
    __builtin_amdgcn_s_barrier();
    buf = nb;
  }

  // epilogue: C/D layout col=lane&15, row=(lane>>4)*4+reg
  #pragma unroll
  for (int m = 0; m < 8; m++){
    int rb = row0 + wm*128 + m*16 + kg*4;
    #pragma unroll
    for (int n = 0; n < 4; n++){
      int cc = col0 + wn*64 + n*16 + lr;
      #pragma unroll
      for (int r = 0; r < 4; r++)
        C[(size_t)(rb + r)*N + cc] = (bf16_t)acc[m][n][r];
    }
  }
}

// ======================================================================
// 128x128 GEMM, ring-3 LDS, counted vmcnt (R6-proven). XOR swizzle
// (r>>1)&3. cmode: 0 XCD-band mapping; 2 causal K-limit.
// ======================================================================
__global__ __launch_bounds__(256) void gemm_bt(const bf16_t* __restrict__ A,
                                               const bf16_t* __restrict__ Bm,
                                               bf16_t* __restrict__ C,
                                               int M, int N, int K,
                                               long sA, long sB, long sC, int cmode){
  __shared__ bf16_t As[3][128*32];
  __shared__ bf16_t Bs[3][128*32];

  int gx = gridDim.x, gy = gridDim.y;
  int nwg = gx * gy * gridDim.z;
  int id  = (blockIdx.z * gy + blockIdx.y) * gx + blockIdx.x;
  int cpx = nwg >> 3;
  int nrb = cpx / gx;
  int x   = id & 7;
  int local = id >> 3;
  int bx  = local / nrb;
  int frow = x * nrb + (local % nrb);
  int by  = frow % gy;
  int z   = frow / gy;

  A  += (size_t)z * sA;
  Bm += (size_t)z * sB;
  C  += (size_t)z * sC;

  int row0 = by * 128, col0 = bx * 128;

  int tid  = threadIdx.x;
  int lane = tid & 63;
  int wave = tid >> 6;
  int wm = wave >> 1, wn = wave & 1;
  int lr = lane & 15, kg = lane >> 4;

  f32x4 acc[4][4] = {};
  int NT = K >> 5;
  if (cmode == 2) { int lim = (row0 + 128) >> 5; NT = NT < lim ? NT : lim; }

  auto stage = [&](int buf, int kt){
    int kk = kt * 32;
    #pragma unroll
    for (int i = 0; i < 2; i++){
      int c  = tid + i*256;
      int r  = c >> 2;
      int scol = ((c & 3) ^ ((r >> 1) & 3)) * 8;
      __builtin_amdgcn_global_load_lds((gvoid_t*)(A  + (size_t)(row0 + r)*K + kk + scol),
                                       (lds_void_t*)(&As[buf][c*8]), 16, 0, 0);
      __builtin_amdgcn_global_load_lds((gvoid_t*)(Bm + (size_t)(col0 + r)*K + kk + scol),
                                       (lds_void_t*)(&Bs[buf][c*8]), 16, 0, 0);
    }
  };

  stage(0, 0);
  stage(1, 1);                                  // NT >= 2 for all our calls
  asm volatile("s_waitcnt vmcnt(4)" ::: "memory");
  __builtin_amdgcn_s_barrier();
  __builtin_amdgcn_sched_barrier(0);

  int b0 = 0, b1 = 1, b2 = 2;
  for (int kt = 0; kt < NT; ++kt){
    if (kt + 2 < NT) stage(b2, kt + 2);
    bf16x8 af[4], bfr[4];
    #pragma unroll
    for (int m = 0; m < 4; m++){
      int r = wm*64 + m*16 + lr;
      af[m] = *reinterpret_cast<const bf16x8*>(&As[b0][r*32 + ((kg ^ ((r >> 1) & 3)) * 8)]);
    }
    #pragma unroll
    for (int n = 0; n < 4; n++){
      int r = wn*64 + n*16 + lr;
      bfr[n] = *reinterpret_cast<const bf16x8*>(&Bs[b0][r*32 + ((kg ^ ((r >> 1) & 3)) * 8)]);
    }
    #pragma unroll
    for (int m = 0; m < 4; m++)
      #pragma unroll
      for (int n = 0; n < 4; n++)
        acc[m][n] = __builtin_amdgcn_mfma_f32_16x16x32_bf16(af[m], bfr[n], acc[m][n], 0, 0, 0);
    if (kt + 1 < NT){
      if (kt + 2 < NT) asm volatile("s_waitcnt vmcnt(4)" ::: "memory");
      else             asm volatile("s_waitcnt vmcnt(0)" ::: "memory");
      __builtin_amdgcn_s_barrier();
      __builtin_amdgcn_sched_barrier(0);
    }
    int tmp = b0; b0 = b1; b1 = b2; b2 = tmp;
  }

  #pragma unroll
  for (int m = 0; m < 4; m++){
    int rb = row0 + wm*64 + m*16 + kg*4;
    #pragma unroll
    for (int n = 0; n < 4; n++){
      int cc = col0 + wn*64 + n*16 + lr;
      #pragma unroll
      for (int r = 0; r < 4; r++)
        C[(size_t)(rb + r)*N + cc] = (bf16_t)acc[m][n][r];
    }
  }
}

// ---------------- merged QKV gate: wave-per-row, 3 sections ----------------
__global__ __launch_bounds__(256) void gate_qkv(const bf16_t* __restrict__ inp,
                                                const bf16_t* __restrict__ c3,
                                                const float* __restrict__ b_q,
                                                const float* __restrict__ b_k,
                                                const float* __restrict__ b_v,
                                                const float* __restrict__ cosT,
                                                const float* __restrict__ sinT,
                                                bf16_t* __restrict__ q_o,
                                                bf16_t* __restrict__ k_o,
                                                bf16_t* __restrict__ v_o,
                                                float rs){
  int wid = threadIdx.x >> 6, l = threadIdx.x & 63;
  int row = blockIdx.x * 4 + wid;
  size_t bi = (size_t)row * H_ + l*12;
  size_t brow = (size_t)row * NQKV + l*12;

  float iv[12];
  #pragma unroll
  for (int i = 0; i < 3; i++){
    u16x4 a = *(const u16x4*)(inp + bi + 4*i);
    #pragma unroll
    for (int j = 0; j < 4; j++) iv[4*i+j] = b2f(a[j]);
  }
  int s = row & (S_ - 1);
  f32x4 cw[3], sw[3];
  #pragma unroll
  for (int i = 0; i < 3; i++){
    cw[i] = *(const f32x4*)(cosT + (size_t)s*H_ + l*12 + 4*i);
    sw[i] = *(const f32x4*)(sinT + (size_t)s*H_ + l*12 + 4*i);
  }

  const float* biasp[3] = {b_q, b_k, b_v};
  bf16_t* outp[3] = {q_o, k_o, v_o};

  #pragma unroll
  for (int sec = 0; sec < 3; sec++){
    size_t bc = brow + (size_t)sec * 2304;
    float cv[12], mv[12], gv[12];
    float gmax = 0.f;
    #pragma unroll
    for (int i = 0; i < 3; i++){
      u16x4 b = *(const u16x4*)(c3 + bc + 4*i);
      u16x4 c = *(const u16x4*)(c3 + bc + 768 + 4*i);
      u16x4 d = *(const u16x4*)(c3 + bc + 1536 + 4*i);
      f32x4 bv = *(const f32x4*)(biasp[sec] + l*12 + 4*i);
      #pragma unroll
      for (int j = 0; j < 4; j++){
        cv[4*i+j] = b2f(b[j]) + bv[j];
        mv[4*i+j] = b2f(c[j]);
        gv[4*i+j] = b2f(d[j]);
        gmax = fmaxf(gmax, fabsf(gv[4*i+j]));
      }
    }
    gmax = waveMax(gmax);
    float rg = 1.f / (gmax + 1e-9f);
    float rt[12], rmax = 0.f;
    #pragma unroll
    for (int j = 0; j < 12; j++){
      rt[j] = mv[j] - fmaxf(gv[j]*rg, 0.f);
      rmax  = fmaxf(rmax, fabsf(rt[j]));
    }
    rmax = waveMax(rmax);
    float rr = 1.f / (rmax + 1e-9f);
    float oscale = (sec == 0) ? rs : 1.0f;
    float val[12];
    #pragma unroll
    for (int j = 0; j < 12; j++) val[j] = (iv[j] + cv[j]) * fmaxf(rt[j]*rr, 0.f) * oscale;

    if (sec < 2){
      #pragma unroll
      for (int i = 0; i < 3; i++){
        u16x4 u;
        #pragma unroll
        for (int j = 0; j < 4; j++){
          int q = 4*i + j;
          float partner = __shfl_xor(val[q], 32);
          if (l < 32) partner = -partner;
          u[j] = f2b(val[q]*cw[i][j] + partner*sw[i][j]);
        }
        *(u16x4*)(outp[sec] + bi + 4*i) = u;
      }
    } else {
      #pragma unroll
      for (int i = 0; i < 3; i++){
        u16x4 u;
        #pragma unroll
        for (int j = 0; j < 4; j++) u[j] = f2b(val[4*i+j]);
        *(u16x4*)(outp[sec] + bi + 4*i) = u;
      }
    }
  }
}

// ---------------- gate branch: wave-per-row ----------------
// mode 2: +residb(bf16) -> outf (fp32)
// mode 3: relu -> outb
// mode 4: +residf(fp32) -> outb2 (bf16 x1) AND LayerNorm -> outb
__global__ __launch_bounds__(256) void gate_kernel(const bf16_t* __restrict__ inp,
                                                   const bf16_t* __restrict__ c3,
                                                   long ldc, int colbase,
                                                   const float* __restrict__ bias,
                                                   const float* __restrict__ residf,
                                                   const bf16_t* __restrict__ residb,
                                                   const float* __restrict__ lnw,
                                                   const float* __restrict__ lnb,
                                                   float* __restrict__ outf,
                                                   bf16_t* __restrict__ outb,
                                                   bf16_t* __restrict__ outb2,
                                                   int mode){
  int wid = threadIdx.x >> 6, l = threadIdx.x & 63;
  int row = blockIdx.x * 4 + wid;
  size_t bi = (size_t)row * H_ + l*12;
  size_t bc = (size_t)row * ldc + colbase + l*12;

  float iv[12], cv[12], mv[12], gv[12];
  float gmax = 0.f;
  #pragma unroll
  for (int i = 0; i < 3; i++){
    u16x4 a = *(const u16x4*)(inp + bi + 4*i);
    u16x4 b = *(const u16x4*)(c3 + bc + 4*i);
    u16x4 c = *(const u16x4*)(c3 + bc + 768 + 4*i);
    u16x4 d = *(const u16x4*)(c3 + bc + 1536 + 4*i);
    f32x4 bv = *(const f32x4*)(bias + l*12 + 4*i);
    #pragma unroll
    for (int j = 0; j < 4; j++){
      iv[4*i+j] = b2f(a[j]); cv[4*i+j] = b2f(b[j]) + bv[j];
      mv[4*i+j] = b2f(c[j]); gv[4*i+j] = b2f(d[j]);
      gmax = fmaxf(gmax, fabsf(gv[4*i+j]));
    }
  }
  gmax = waveMax(gmax);
  float rg = 1.f / (gmax + 1e-9f);

  float rt[12], rmax = 0.f;
  #pragma unroll
  for (int j = 0; j < 12; j++){
    rt[j] = mv[j] - fmaxf(gv[j]*rg, 0.f);
    rmax  = fmaxf(rmax, fabsf(rt[j]));
  }
  rmax = waveMax(rmax);
  float rr = 1.f / (rmax + 1e-9f);

  float val[12];
  #pragma unroll
  for (int j = 0; j < 12; j++) val[j] = (iv[j] + cv[j]) * fmaxf(rt[j]*rr, 0.f);

  if (mode == 3){
    #pragma unroll
    for (int i = 0; i < 3; i++){
      u16x4 u;
      #pragma unroll
      for (int j = 0; j < 4; j++) u[j] = f2b(fmaxf(val[4*i+j], 0.f));
      *(u16x4*)(outb + bi + 4*i) = u;
    }
  } else if (mode == 2){
    #pragma unroll
    for (int i = 0; i < 3; i++){
      u16x4 rv = *(const u16x4*)(residb + bi + 4*i);
      f32x4 ov;
      #pragma unroll
      for (int j = 0; j < 4; j++) ov[j] = val[4*i+j] + b2f(rv[j]);
      *(f32x4*)(outf + bi + 4*i) = ov;
    }
  } else { // mode 4
    float xv[12];
    #pragma unroll
    for (int i = 0; i < 3; i++){
      f32x4 rv = *(const f32x4*)(residf + bi + 4*i);
      u16x4 ov;
      #pragma unroll
      for (int j = 0; j < 4; j++){ xv[4*i+j] = val[4*i+j] + rv[j]; ov[j] = f2b(xv[4*i+j]); }
      *(u16x4*)(outb2 + bi + 4*i) = ov;
    }
    float s1 = 0.f, s2 = 0.f;
    #pragma unroll
    for (int j = 0; j < 12; j++){ s1 += xv[j]; s2 += xv[j]*xv[j]; }
    s1 = waveSum(s1); s2 = waveSum(s2);
    float mu = s1 * (1.f/H_), var = s2 * (1.f/H_) - mu*mu;
    float rstd = rsqrtf(var + 1e-5f);
    #pragma unroll
    for (int i = 0; i < 3; i++){
      f32x4 wv = *(const f32x4*)(lnw + l*12 + 4*i);
      f32x4 bv = *(const f32x4*)(lnb + l*12 + 4*i);
      u16x4 u;
      #pragma unroll
      for (int j = 0; j < 4; j++) u[j] = f2b((xv[4*i+j]-mu)*rstd*wv[j] + bv[j]);
      *(u16x4*)(outb + bi + 4*i) = u;
    }
  }
}

// ---------------- single-pass causal softmax: 8 cols/thread in registers ----------------
__global__ __launch_bounds__(256) void softmax_causal(const bf16_t* __restrict__ sc,
                                                      bf16_t* __restrict__ P){
  __shared__ float red[4];
  int r = blockIdx.x, b = blockIdx.y, t = threadIdx.x;
  const bf16_t* srow = sc + (size_t)b*SS + (size_t)r * S_;
  bf16_t* prow = P + (size_t)b*SS + (size_t)r * S_;
  int n = r + 1;
  int fill = ((r >> 7) + 1) << 7;          // PV reads k < row0+128; zero up to there
  int c0 = t * 8;

  float v[8];
  float m = -1e30f;
  if (c0 < n){
    u16x8 u = *(const u16x8*)(srow + c0);
    #pragma unroll
    for (int j = 0; j < 8; j++){
      v[j] = (c0 + j < n) ? b2f(u[j]) : -1e30f;
      m = fmaxf(m, v[j]);
    }
  } else {
    #pragma unroll
    for (int j = 0; j < 8; j++) v[j] = -1e30f;
  }
  m = blockReduce<true>(m, red);
  float sum = 0.f;
  #pragma unroll
  for (int j = 0; j < 8; j++){
    v[j] = (v[j] > -1e29f) ? __expf(v[j] - m) : 0.f;
    sum += v[j];
  }
  sum = blockReduce<false>(sum, red);
  float inv = 1.f / sum;
  if (c0 < fill){
    u16x8 u;
    #pragma unroll
    for (int j = 0; j < 8; j++) u[j] = f2b(v[j] * inv);
    *(u16x8*)(prow + c0) = u;
  }
}

// ---------------- 32x32 tiled transpose [B,S,H] -> [B,H,S] ----------------
__global__ __launch_bounds__(256) void transpose_bf(const bf16_t* __restrict__ in,
                                                    bf16_t* __restrict__ out){
  __shared__ bf16_t tile[32][33];
  int bz = blockIdx.z;
  const bf16_t* I = in  + (size_t)bz * SH;
  bf16_t*       O = out + (size_t)bz * SH;
  int s0 = blockIdx.x*32, h0 = blockIdx.y*32;
  int tx = threadIdx.x, ty = threadIdx.y;
  #pragma unroll
  for (int k = 0; k < 4; k++)
    tile[ty + 8*k][tx] = I[(size_t)(s0 + ty + 8*k)*H_ + h0 + tx];
  __syncthreads();
  #pragma unroll
  for (int k = 0; k < 4; k++)
    O[(size_t)(h0 + ty + 8*k)*S_ + s0 + tx] = tile[tx][ty + 8*k];
}

// ---------------- launch ----------------
extern "C" void kernel_launch(void* const* d_in, const int* in_sizes, int n_in,
                              void* d_out, int out_size, void* d_ws, size_t ws_size,
                              hipStream_t stream){
  const float* x    = (const float*)d_in[0];
  const float* cosT = (const float*)d_in[1];
  const float* sinT = (const float*)d_in[2];
  const float* ln1w = (const float*)d_in[3];
  const float* ln1b = (const float*)d_in[4];
  const float* ln2w = (const float*)d_in[5];
  const float* ln2b = (const float*)d_in[6];

  W18 wp; const float* bias[6];
  for (int i = 0; i < 6; i++){
    const float* proto = (const float*)d_in[7 + 4*i + 0];
    const float* gatep = (const float*)d_in[7 + 4*i + 1];
    const float* muw   = (const float*)d_in[7 + 4*i + 2];
    bias[i]            = (const float*)d_in[7 + 4*i + 3];
    wp.p[i*3 + 0] = muw;    // comp
    wp.p[i*3 + 1] = proto;  // match (scaled by rs at conversion)
    wp.p[i*3 + 2] = gatep;  // gate
  }

  hipFuncSetAttribute((const void*)gemm256ph, hipFuncAttributeMaxDynamicSharedMemorySize, 131072);

  char* w = (char*)d_ws;
  auto alloc = [&](size_t bytes){ void* r = (void*)w; w += (bytes + 255) & ~(size_t)255; return r; };
  bf16_t* w_bf   = (bf16_t*)alloc((size_t)18 * HH * 2);      // [13824, 768]
  bf16_t* a_bf   = (bf16_t*)alloc(MN * 2);
  bf16_t* h_bf   = (bf16_t*)alloc(MN * 2);
  bf16_t* c3b    = (bf16_t*)alloc((size_t)M_ * NQKV * 2);    // logits; overlays scores+P
  bf16_t* q_bf   = (bf16_t*)alloc(MN * 2);
  bf16_t* k_bf   = (bf16_t*)alloc(MN * 2);
  bf16_t* v_bf   = (bf16_t*)alloc(MN * 2);
  bf16_t* vt     = (bf16_t*)alloc(MN * 2);
  bf16_t* attn_b = (bf16_t*)alloc(MN * 2);
  bf16_t* x1b    = (bf16_t*)alloc(MN * 2);
  (void)ws_size;
  bf16_t* sc_bf = c3b;
  bf16_t* p_bf  = c3b + B_ * SS;

  const float rs = 1.0f / sqrtf((float)H_);

  conv_weights<<<dim3(HH/1024, 18), 256, 0, stream>>>(wp, w_bf, rs);
  ln_kernel<<<M_/4, 256, 0, stream>>>(x, ln1w, ln1b, a_bf);

  // QKV fused SPL: c3b[M, 6912]  — 8-phase 256^2 BK=64 kernel (R9 config)
  gemm256ph<<<dim3(NQKV/256, M_/256, 1), 512, 131072, stream>>>(
      a_bf, w_bf, c3b, M_, NQKV, H_, 0, 0, 0, 0);
  gate_qkv<<<M_/4, 256, 0, stream>>>(a_bf, c3b, bias[0], bias[1], bias[2],
                                     cosT, sinT, q_bf, k_bf, v_bf, rs);

  transpose_bf<<<dim3(S_/32, H_/32, B_), dim3(32, 8), 0, stream>>>(v_bf, vt);

  // QK^T (scale folded into q) — 8-phase, triangle-compacted grid (R9 config)
  gemm256ph<<<dim3(36*B_, 1, 1), 512, 131072, stream>>>(
      q_bf, k_bf, sc_bf, S_, S_, H_, (long)SH, (long)SH, (long)SS, 1);

  softmax_causal<<<dim3(S_, B_), 256, 0, stream>>>(sc_bf, p_bf);

  // PV (K limited causally) — ring-3 128^2
  gemm_bt<<<dim3(H_/128, S_/128, B_), 256, 0, stream>>>(
      p_bf, vt, attn_b, S_, H_, S_, (long)SS, (long)SH, (long)SH, 2);

  // o-SPL + gate(+residual x) + fused LN2 -> x1b (bf16) and a_bf (LN2 out)
  gemm_bt<<<dim3(N3/128, M_/128, 1), 256, 0, stream>>>(
      attn_b, w_bf + (size_t)9*HH, c3b, M_, N3, H_, 0, 0, 0, 0);
  gate_kernel<<<M_/4, 256, 0, stream>>>(attn_b, c3b, N3, 0, bias[3],
      x, nullptr, ln2w, ln2b, nullptr, a_bf, x1b, 4);

  // f1-SPL + gate + relu -> h_bf
  gemm_bt<<<dim3(N3/128, M_/128, 1), 256, 0, stream>>>(
      a_bf, w_bf + (size_t)12*HH, c3b, M_, N3, H_, 0, 0, 0, 0);
  gate_kernel<<<M_/4, 256, 0, stream>>>(a_bf, c3b, N3, 0, bias[4],
      nullptr, nullptr, nullptr, nullptr, nullptr, h_bf, nullptr, 3);

  // f2-SPL + gate(+residual x1b) -> d_out (fp32)
  gemm_bt<<<dim3(N3/128, M_/128, 1), 256, 0, stream>>>(
      h_bf, w_bf + (size_t)15*HH, c3b, M_, N3, H_, 0, 0, 0, 0);
  gate_kernel<<<M_/4, 256, 0, stream>>>(h_bf, c3b, N3, 0, bias[5],
      nullptr, x1b, nullptr, nullptr, (float*)d_out, nullptr, nullptr, 2);
}